// Round 1
// baseline (659.139 us; speedup 1.0000x reference)
//
#include <hip/hip_runtime.h>
#include <stdint.h>

// ---------------------------------------------------------------------------
// PrimitiveFitting: voxel-hash primitive fitting (mu + scaled-eigvec R).
//
// Pipeline (all on `stream`):
//   1. min/max reduce of points (order-preserving uint-mapped atomics)
//   2. prep: pc_min, dims, key-space size K  (must be bitwise == numpy ref)
//   3. mark: bitmap[key] |= 1  for each point's voxel key
//   4. scanA/scanB: popcount prefix over bitmap words -> rank(key) = sorted
//      unique index (== jnp.unique + searchsorted), M = #unique
//   5. scatter: each point adds exp(-d2/decay2)-weighted moments into the
//      occupied voxels among its 27 neighbors (float atomics; sparse)
//   6. finalize: mu = wp/ws, sigma = wo/ws - mu mu^T, 3x3 Jacobi eigen,
//      sort |lambda| desc, S = max(sqrt|l|,1e-6), det<0 -> flip 3rd col.
// ---------------------------------------------------------------------------

#define WMAX  5400064u        // bitmap words: >= ceil(10*257^3 / 32), 256-multiple
#define PBLK  21094           // WMAX / 256

struct Hdr {
  unsigned umin[4];
  unsigned umax[4];
  float    pc_min[4];
  int      dims[4];
  int      K, W, M;
};

__device__ __forceinline__ unsigned fkey_map(float f) {
  unsigned u = __float_as_uint(f);
  return (u & 0x80000000u) ? ~u : (u | 0x80000000u);
}
__device__ __forceinline__ float fkey_unmap(unsigned u) {
  unsigned b = (u & 0x80000000u) ? (u ^ 0x80000000u) : ~u;
  return __uint_as_float(b);
}

__global__ void k_init_hdr(Hdr* h) {
  int t = threadIdx.x;
  if (t < 4) { h->umin[t] = 0xFFFFFFFFu; h->umax[t] = 0u; }
}

__global__ void k_minmax(const float4* __restrict__ pts, int n, Hdr* h) {
  float mn[4] = { INFINITY,  INFINITY,  INFINITY,  INFINITY};
  float mx[4] = {-INFINITY, -INFINITY, -INFINITY, -INFINITY};
  for (int i = blockIdx.x * blockDim.x + threadIdx.x; i < n;
       i += gridDim.x * blockDim.x) {
    float4 p = pts[i];
    mn[0] = fminf(mn[0], p.x); mx[0] = fmaxf(mx[0], p.x);
    mn[1] = fminf(mn[1], p.y); mx[1] = fmaxf(mx[1], p.y);
    mn[2] = fminf(mn[2], p.z); mx[2] = fmaxf(mx[2], p.z);
    mn[3] = fminf(mn[3], p.w); mx[3] = fmaxf(mx[3], p.w);
  }
  #pragma unroll
  for (int off = 32; off > 0; off >>= 1) {
    #pragma unroll
    for (int c = 0; c < 4; ++c) {
      mn[c] = fminf(mn[c], __shfl_down(mn[c], off));
      mx[c] = fmaxf(mx[c], __shfl_down(mx[c], off));
    }
  }
  if ((threadIdx.x & 63) == 0) {
    #pragma unroll
    for (int c = 0; c < 4; ++c) {
      atomicMin(&h->umin[c], fkey_map(mn[c]));
      atomicMax(&h->umax[c], fkey_map(mx[c]));
    }
  }
}

__global__ void k_prep(Hdr* h) {
  if (threadIdx.x != 0 || blockIdx.x != 0) return;
  const float vs[4] = {1.0f, 0.4f, 0.4f, 0.4f};
  int dims[4];
  #pragma unroll
  for (int c = 0; c < 4; ++c) {
    float mn = fkey_unmap(h->umin[c]);
    float mx = fkey_unmap(h->umax[c]);
    float pmin = mn - vs[c] * 2.0f;       // exact: vs*2 representable, sub IEEE
    float pmax = mx + vs[c] * 2.0f;
    h->pc_min[c] = pmin;
    dims[c] = (int)rintf((pmax - pmin) / vs[c]) + 3;   // == np.round (half-even)
    h->dims[c] = dims[c];
  }
  int K = dims[0];
  #pragma unroll
  for (int c = 1; c < 4; ++c) K *= dims[c];
  h->K = K;
  h->W = (K + 31) >> 5;
}

__device__ __forceinline__ void point_coors(float4 p, const Hdr* __restrict__ h,
                                            int c[4]) {
  // Must match numpy bitwise: f32 subtract, f32 IEEE divide, rint (half-even).
  c[0] = (int)rintf((p.x - h->pc_min[0]) / 1.0f) + 1;
  c[1] = (int)rintf((p.y - h->pc_min[1]) / 0.4f) + 1;
  c[2] = (int)rintf((p.z - h->pc_min[2]) / 0.4f) + 1;
  c[3] = (int)rintf((p.w - h->pc_min[3]) / 0.4f) + 1;
}

__global__ void k_mark(const float4* __restrict__ pts, int n,
                       const Hdr* __restrict__ h, unsigned* __restrict__ bm) {
  int i = blockIdx.x * 256 + threadIdx.x;
  if (i >= n) return;
  float4 p = pts[i];
  int c[4]; point_coors(p, h, c);
  int key = ((c[0] * h->dims[1] + c[1]) * h->dims[2] + c[2]) * h->dims[3] + c[3];
  unsigned uk = (unsigned)key;
  if (uk >= WMAX * 32u) return;   // safety (never taken for valid data)
  atomicOr(&bm[uk >> 5], 1u << (uk & 31u));
}

// exclusive intra-block popcount prefix -> rank[w]; block totals -> part[b]
__global__ void k_scanA(const unsigned* __restrict__ bm,
                        unsigned* __restrict__ rank,
                        unsigned* __restrict__ part) {
  __shared__ unsigned s[256];
  int t = threadIdx.x;
  unsigned w = blockIdx.x * 256u + t;
  unsigned pc = __popc(bm[w]);
  s[t] = pc; __syncthreads();
  for (int off = 1; off < 256; off <<= 1) {
    unsigned v = (t >= off) ? s[t - off] : 0u;
    __syncthreads();
    s[t] += v;
    __syncthreads();
  }
  rank[w] = s[t] - pc;
  if (t == 255) part[blockIdx.x] = s[255];
}

// exclusive scan of block totals (in place) + total unique count M
__global__ void k_scanB(unsigned* __restrict__ part, Hdr* h) {
  __shared__ unsigned s[256];
  __shared__ unsigned carry;
  int t = threadIdx.x;
  if (t == 0) carry = 0u;
  __syncthreads();
  for (int base = 0; base < PBLK; base += 256) {
    unsigned v = (base + t < PBLK) ? part[base + t] : 0u;
    s[t] = v; __syncthreads();
    for (int off = 1; off < 256; off <<= 1) {
      unsigned x = (t >= off) ? s[t - off] : 0u;
      __syncthreads();
      s[t] += x;
      __syncthreads();
    }
    if (base + t < PBLK) part[base + t] = s[t] - v + carry;
    __syncthreads();
    if (t == 0) carry += s[255];
    __syncthreads();
  }
  if (t == 0) h->M = (int)carry;
}

__global__ void k_scatter(const float4* __restrict__ pts, int n,
                          const Hdr* __restrict__ h,
                          const unsigned* __restrict__ bm,
                          const unsigned* __restrict__ rank,
                          const unsigned* __restrict__ part,
                          float* __restrict__ wsum, float* __restrict__ wp,
                          float* __restrict__ wo) {
  int i = blockIdx.x * 256 + threadIdx.x;
  if (i >= n) return;
  float4 p = pts[i];
  int c[4]; point_coors(p, h, c);
  int d1 = h->dims[1], d2 = h->dims[2], d3 = h->dims[3];
  float m1 = h->pc_min[1], m2 = h->pc_min[2], m3 = h->pc_min[3];
  const float gg = 0.4f * 0.4f;
  const float decay2 = (gg + gg + gg) * 0.25f;   // == sum(vs[1:]^2)/4 bitwise
  int base0 = c[0] * d1;
  for (int dx = -1; dx <= 1; ++dx)
    for (int dy = -1; dy <= 1; ++dy)
      for (int dz = -1; dz <= 1; ++dz) {
        int n1 = c[1] + dx, n2 = c[2] + dy, n3 = c[3] + dz;
        int key = ((base0 + n1) * d2 + n2) * d3 + n3;
        unsigned uk = (unsigned)key;
        if (uk >= WMAX * 32u) continue;          // safety
        unsigned word = bm[uk >> 5];
        unsigned bit = uk & 31u;
        if (!((word >> bit) & 1u)) continue;     // neighbor voxel unoccupied
        int r = (int)(part[uk >> 13] + rank[uk >> 5] +
                      __popc(word & ((1u << bit) - 1u)));
        float cx = (float)(n1 - 1) * 0.4f + m1;
        float cy = (float)(n2 - 1) * 0.4f + m2;
        float cz = (float)(n3 - 1) * 0.4f + m3;
        float ex = p.y - cx, ey = p.z - cy, ez = p.w - cz;
        float dd = ex * ex + ey * ey + ez * ez;
        float wgt = expf(-dd / decay2);
        atomicAdd(&wsum[r], wgt);
        atomicAdd(&wp[4 * r + 0], wgt * p.x);
        atomicAdd(&wp[4 * r + 1], wgt * p.y);
        atomicAdd(&wp[4 * r + 2], wgt * p.z);
        atomicAdd(&wp[4 * r + 3], wgt * p.w);
        atomicAdd(&wo[6 * r + 0], wgt * p.y * p.y);
        atomicAdd(&wo[6 * r + 1], wgt * p.y * p.z);
        atomicAdd(&wo[6 * r + 2], wgt * p.y * p.w);
        atomicAdd(&wo[6 * r + 3], wgt * p.z * p.z);
        atomicAdd(&wo[6 * r + 4], wgt * p.z * p.w);
        atomicAdd(&wo[6 * r + 5], wgt * p.w * p.w);
      }
}

__global__ void k_finalize(const Hdr* __restrict__ h,
                           const float* __restrict__ wsum,
                           const float* __restrict__ wp,
                           const float* __restrict__ wo,
                           float* __restrict__ out_mu,
                           float* __restrict__ out_R, int n) {
  int i = blockIdx.x * 256 + threadIdx.x;
  if (i >= n) return;
  float ws = wsum[i];
  bool ok = (i < h->M) && (ws > 0.0f);
  float* mu_o = out_mu + (size_t)i * 4;
  float* R_o = out_R + (size_t)i * 9;
  if (!ok) {
    mu_o[0] = mu_o[1] = mu_o[2] = mu_o[3] = 0.0f;
    #pragma unroll
    for (int k = 0; k < 9; ++k) R_o[k] = 0.0f;
    return;
  }
  float mu0 = wp[4 * i + 0] / ws;
  float mu1 = wp[4 * i + 1] / ws;
  float mu2 = wp[4 * i + 2] / ws;
  float mu3 = wp[4 * i + 3] / ws;
  float A[3][3];
  A[0][0] = wo[6 * i + 0] / ws - mu1 * mu1;
  A[0][1] = A[1][0] = wo[6 * i + 1] / ws - mu1 * mu2;
  A[0][2] = A[2][0] = wo[6 * i + 2] / ws - mu1 * mu3;
  A[1][1] = wo[6 * i + 3] / ws - mu2 * mu2;
  A[1][2] = A[2][1] = wo[6 * i + 4] / ws - mu2 * mu3;
  A[2][2] = wo[6 * i + 5] / ws - mu3 * mu3;

  float V[3][3] = {{1.f, 0.f, 0.f}, {0.f, 1.f, 0.f}, {0.f, 0.f, 1.f}};
  for (int sweep = 0; sweep < 8; ++sweep) {
    #pragma unroll
    for (int pi = 0; pi < 3; ++pi) {
      int p = (pi == 2) ? 1 : 0;
      int q = (pi == 0) ? 1 : 2;
      float apq = A[p][q];
      if (apq == 0.0f) continue;
      float app = A[p][p], aqq = A[q][q];
      float theta = (aqq - app) / (2.0f * apq);
      float t = 1.0f / (fabsf(theta) + sqrtf(theta * theta + 1.0f));
      if (theta < 0.0f) t = -t;
      float cth = 1.0f / sqrtf(t * t + 1.0f);
      float sth = t * cth;
      A[p][p] = app - t * apq;
      A[q][q] = aqq + t * apq;
      A[p][q] = A[q][p] = 0.0f;
      int k = 3 - p - q;
      float akp = A[k][p], akq = A[k][q];
      A[k][p] = A[p][k] = cth * akp - sth * akq;
      A[k][q] = A[q][k] = sth * akp + cth * akq;
      #pragma unroll
      for (int r = 0; r < 3; ++r) {
        float vp = V[r][p], vq = V[r][q];
        V[r][p] = cth * vp - sth * vq;
        V[r][q] = sth * vp + cth * vq;
      }
    }
  }
  float l[3] = {A[0][0], A[1][1], A[2][2]};
  float a[3] = {fabsf(l[0]), fabsf(l[1]), fabsf(l[2])};
  int idx[3] = {0, 1, 2};
  if (a[idx[0]] < a[idx[1]]) { int t = idx[0]; idx[0] = idx[1]; idx[1] = t; }
  if (a[idx[1]] < a[idx[2]]) { int t = idx[1]; idx[1] = idx[2]; idx[2] = t; }
  if (a[idx[0]] < a[idx[1]]) { int t = idx[0]; idx[0] = idx[1]; idx[1] = t; }
  float S0 = fmaxf(sqrtf(a[idx[0]]), 1e-6f);
  float S1 = fmaxf(sqrtf(a[idx[1]]), 1e-6f);
  float S2 = fmaxf(sqrtf(a[idx[2]]), 1e-6f);
  float U[3][3];
  #pragma unroll
  for (int r = 0; r < 3; ++r) {
    U[r][0] = V[r][idx[0]];
    U[r][1] = V[r][idx[1]];
    U[r][2] = V[r][idx[2]];
  }
  float det = U[0][0] * (U[1][1] * U[2][2] - U[1][2] * U[2][1])
            - U[0][1] * (U[1][0] * U[2][2] - U[1][2] * U[2][0])
            + U[0][2] * (U[1][0] * U[2][1] - U[1][1] * U[2][0]);
  float f2 = (det < 0.0f) ? -1.0f : 1.0f;
  mu_o[0] = mu0; mu_o[1] = mu1; mu_o[2] = mu2; mu_o[3] = mu3;
  R_o[0] = U[0][0] * S0; R_o[1] = U[0][1] * S1; R_o[2] = U[0][2] * S2 * f2;
  R_o[3] = U[1][0] * S0; R_o[4] = U[1][1] * S1; R_o[5] = U[1][2] * S2 * f2;
  R_o[6] = U[2][0] * S0; R_o[7] = U[2][1] * S1; R_o[8] = U[2][2] * S2 * f2;
}

extern "C" void kernel_launch(void* const* d_in, const int* in_sizes, int n_in,
                              void* d_out, int out_size, void* d_ws,
                              size_t ws_size, hipStream_t stream) {
  const float4* pts = (const float4*)d_in[0];
  int n = in_sizes[0] / 4;
  float* out = (float*)d_out;
  float* outR = out + (size_t)4 * n;

  char* ws = (char*)d_ws;
  Hdr* hdr = (Hdr*)ws;
  size_t off = 256;
  unsigned* bm = (unsigned*)(ws + off);   off += (size_t)WMAX * 4;   // 21.6 MB
  unsigned* rank = (unsigned*)(ws + off); off += (size_t)WMAX * 4;   // 21.6 MB
  unsigned* part = (unsigned*)(ws + off); off += (size_t)24576 * 4;  // 96 KB
  float* acc = (float*)(ws + off);
  float* wsum = acc;            // n
  float* wp = acc + n;          // 4n
  float* wo = acc + 5 * (size_t)n;  // 6n
  size_t needed = off + (size_t)n * 11 * 4;
  if (ws_size < needed) return;  // workspace too small (should not happen)

  hipMemsetAsync(bm, 0, (size_t)WMAX * 4, stream);
  hipMemsetAsync(acc, 0, (size_t)n * 11 * 4, stream);
  k_init_hdr<<<1, 64, 0, stream>>>(hdr);

  int nb = (n + 255) / 256;
  k_minmax<<<nb, 256, 0, stream>>>(pts, n, hdr);
  k_prep<<<1, 64, 0, stream>>>(hdr);
  k_mark<<<nb, 256, 0, stream>>>(pts, n, hdr, bm);
  k_scanA<<<PBLK, 256, 0, stream>>>(bm, rank, part);
  k_scanB<<<1, 256, 0, stream>>>(part, hdr);
  k_scatter<<<nb, 256, 0, stream>>>(pts, n, hdr, bm, rank, part, wsum, wp, wo);
  k_finalize<<<nb, 256, 0, stream>>>(hdr, wsum, wp, wo, out, outR, n);
}

// Round 2
// 330.634 us; speedup vs baseline: 1.9936x; 1.9936x over previous
//
#include <hip/hip_runtime.h>
#include <stdint.h>

// ---------------------------------------------------------------------------
// PrimitiveFitting: voxel-hash primitive fitting (mu + scaled-eigvec R).
//
//   1. minmax: 64-block grid-stride + LDS block reduce -> 512 atomics total
//      (R1 post-mortem: 25k same-address atomics serialized -> 286us; now ~4us)
//   2. prep: pc_min, dims, key-space K (bitwise == numpy reference)
//   3. mark: bitmap[key] |= 1
//   4. scanA: per-256-word-block popcount prefix (rank u16) + block totals
//   5. scanB: single block, thread-sequential chunks + one LDS scan
//   6. scatter: 27-neighbor Gaussian-weighted moment atomics (sparse)
//   7. finalize: mu, sigma, 3x3 Jacobi eigen, |l| desc sort, det flip
// ---------------------------------------------------------------------------

#define WMAX  5400064u        // bitmap words: >= ceil(10*258^3 / 32), 256-mult
#define PBLK  21094           // WMAX / 256
#define CHUNK 83              // ceil(PBLK / 256)

struct Hdr {
  unsigned umin[4];           // offset 0  : memset 0xFF
  unsigned umax[4];           // offset 16 : memset 0x00
  float    pc_min[4];
  int      dims[4];
  int      K, W, M;
};

__device__ __forceinline__ unsigned fkey_map(float f) {
  unsigned u = __float_as_uint(f);
  return (u & 0x80000000u) ? ~u : (u | 0x80000000u);
}
__device__ __forceinline__ float fkey_unmap(unsigned u) {
  unsigned b = (u & 0x80000000u) ? (u ^ 0x80000000u) : ~u;
  return __uint_as_float(b);
}

// 64 blocks x 256 threads; block-level LDS reduce; 8 atomics per block.
__global__ void k_minmax(const float4* __restrict__ pts, int n, Hdr* h) {
  __shared__ unsigned smem[4 * 8];   // [wave][8] mapped-uint mn0..3, mx0..3
  float mn[4] = { INFINITY,  INFINITY,  INFINITY,  INFINITY};
  float mx[4] = {-INFINITY, -INFINITY, -INFINITY, -INFINITY};
  for (int i = blockIdx.x * blockDim.x + threadIdx.x; i < n;
       i += gridDim.x * blockDim.x) {
    float4 p = pts[i];
    mn[0] = fminf(mn[0], p.x); mx[0] = fmaxf(mx[0], p.x);
    mn[1] = fminf(mn[1], p.y); mx[1] = fmaxf(mx[1], p.y);
    mn[2] = fminf(mn[2], p.z); mx[2] = fmaxf(mx[2], p.z);
    mn[3] = fminf(mn[3], p.w); mx[3] = fmaxf(mx[3], p.w);
  }
  #pragma unroll
  for (int off = 32; off > 0; off >>= 1) {
    #pragma unroll
    for (int c = 0; c < 4; ++c) {
      mn[c] = fminf(mn[c], __shfl_down(mn[c], off));
      mx[c] = fmaxf(mx[c], __shfl_down(mx[c], off));
    }
  }
  int wave = threadIdx.x >> 6;
  if ((threadIdx.x & 63) == 0) {
    #pragma unroll
    for (int c = 0; c < 4; ++c) {
      smem[wave * 8 + c]     = fkey_map(mn[c]);
      smem[wave * 8 + 4 + c] = fkey_map(mx[c]);
    }
  }
  __syncthreads();
  int t = threadIdx.x;
  if (t < 4) {             // min components
    unsigned u = smem[t];
    #pragma unroll
    for (int w = 1; w < 4; ++w) u = min(u, smem[w * 8 + t]);
    atomicMin(&h->umin[t], u);
  } else if (t < 8) {      // max components
    unsigned u = smem[t];
    #pragma unroll
    for (int w = 1; w < 4; ++w) u = max(u, smem[w * 8 + t]);
    atomicMax(&h->umax[t - 4], u);
  }
}

__global__ void k_prep(Hdr* h) {
  if (threadIdx.x != 0 || blockIdx.x != 0) return;
  const float vs[4] = {1.0f, 0.4f, 0.4f, 0.4f};
  int dims[4];
  #pragma unroll
  for (int c = 0; c < 4; ++c) {
    float mn = fkey_unmap(h->umin[c]);
    float mx = fkey_unmap(h->umax[c]);
    float pmin = mn - vs[c] * 2.0f;
    float pmax = mx + vs[c] * 2.0f;
    h->pc_min[c] = pmin;
    dims[c] = (int)rintf((pmax - pmin) / vs[c]) + 3;   // == np.round half-even
    h->dims[c] = dims[c];
  }
  int K = dims[0];
  #pragma unroll
  for (int c = 1; c < 4; ++c) K *= dims[c];
  h->K = K;
  h->W = (K + 31) >> 5;
}

__device__ __forceinline__ void point_coors(float4 p, const Hdr* __restrict__ h,
                                            int c[4]) {
  // Must match numpy bitwise: f32 subtract, IEEE f32 divide, rint (half-even).
  c[0] = (int)rintf((p.x - h->pc_min[0]) / 1.0f) + 1;
  c[1] = (int)rintf((p.y - h->pc_min[1]) / 0.4f) + 1;
  c[2] = (int)rintf((p.z - h->pc_min[2]) / 0.4f) + 1;
  c[3] = (int)rintf((p.w - h->pc_min[3]) / 0.4f) + 1;
}

__global__ void k_mark(const float4* __restrict__ pts, int n,
                       const Hdr* __restrict__ h, unsigned* __restrict__ bm) {
  int i = blockIdx.x * 256 + threadIdx.x;
  if (i >= n) return;
  float4 p = pts[i];
  int c[4]; point_coors(p, h, c);
  int key = ((c[0] * h->dims[1] + c[1]) * h->dims[2] + c[2]) * h->dims[3] + c[3];
  unsigned uk = (unsigned)key;
  if (uk >= WMAX * 32u) return;   // safety (never taken for valid data)
  atomicOr(&bm[uk >> 5], 1u << (uk & 31u));
}

// intra-block (256-word) exclusive popcount prefix -> rank16; totals -> part
__global__ void k_scanA(const unsigned* __restrict__ bm,
                        unsigned short* __restrict__ rank16,
                        unsigned* __restrict__ part) {
  __shared__ unsigned s[256];
  int t = threadIdx.x;
  unsigned w = blockIdx.x * 256u + t;
  unsigned pc = __popc(bm[w]);
  s[t] = pc; __syncthreads();
  for (int off = 1; off < 256; off <<= 1) {
    unsigned v = (t >= off) ? s[t - off] : 0u;
    __syncthreads();
    s[t] += v;
    __syncthreads();
  }
  rank16[w] = (unsigned short)(s[t] - pc);   // max 8192, fits u16
  if (t == 255) part[blockIdx.x] = s[255];
}

// single block: thread-sequential chunk sums + one LDS scan + write-back
__global__ void k_scanB(unsigned* __restrict__ part, Hdr* h) {
  __shared__ unsigned s[256];
  int t = threadIdx.x;
  int lo = t * CHUNK;
  int hi = min(lo + CHUNK, PBLK);
  unsigned local[CHUNK];
  unsigned sum = 0;
  for (int j = lo; j < hi; ++j) { local[j - lo] = part[j]; sum += local[j - lo]; }
  s[t] = sum; __syncthreads();
  for (int off = 1; off < 256; off <<= 1) {
    unsigned v = (t >= off) ? s[t - off] : 0u;
    __syncthreads();
    s[t] += v;
    __syncthreads();
  }
  unsigned run = s[t] - sum;    // exclusive prefix of this thread's chunk
  for (int j = lo; j < hi; ++j) {
    unsigned v = local[j - lo];
    part[j] = run;
    run += v;
  }
  if (t == 255) h->M = (int)s[255];
}

__global__ void k_scatter(const float4* __restrict__ pts, int n,
                          const Hdr* __restrict__ h,
                          const unsigned* __restrict__ bm,
                          const unsigned short* __restrict__ rank16,
                          const unsigned* __restrict__ part,
                          float* __restrict__ wsum, float* __restrict__ wp,
                          float* __restrict__ wo) {
  int i = blockIdx.x * 256 + threadIdx.x;
  if (i >= n) return;
  float4 p = pts[i];
  int c[4]; point_coors(p, h, c);
  int d1 = h->dims[1], d2 = h->dims[2], d3 = h->dims[3];
  float m1 = h->pc_min[1], m2 = h->pc_min[2], m3 = h->pc_min[3];
  const float gg = 0.4f * 0.4f;
  const float decay2 = (gg + gg + gg) * 0.25f;   // bitwise == ref
  int base0 = c[0] * d1;
  for (int dx = -1; dx <= 1; ++dx)
    for (int dy = -1; dy <= 1; ++dy)
      for (int dz = -1; dz <= 1; ++dz) {
        int n1 = c[1] + dx, n2 = c[2] + dy, n3 = c[3] + dz;
        int key = ((base0 + n1) * d2 + n2) * d3 + n3;
        unsigned uk = (unsigned)key;
        if (uk >= WMAX * 32u) continue;          // safety
        unsigned word = bm[uk >> 5];
        unsigned bit = uk & 31u;
        if (!((word >> bit) & 1u)) continue;     // neighbor voxel unoccupied
        int r = (int)(part[uk >> 13] + (unsigned)rank16[uk >> 5] +
                      __popc(word & ((1u << bit) - 1u)));
        float cx = (float)(n1 - 1) * 0.4f + m1;
        float cy = (float)(n2 - 1) * 0.4f + m2;
        float cz = (float)(n3 - 1) * 0.4f + m3;
        float ex = p.y - cx, ey = p.z - cy, ez = p.w - cz;
        float dd = ex * ex + ey * ey + ez * ez;
        float wgt = expf(-dd / decay2);
        atomicAdd(&wsum[r], wgt);
        atomicAdd(&wp[4 * r + 0], wgt * p.x);
        atomicAdd(&wp[4 * r + 1], wgt * p.y);
        atomicAdd(&wp[4 * r + 2], wgt * p.z);
        atomicAdd(&wp[4 * r + 3], wgt * p.w);
        atomicAdd(&wo[6 * r + 0], wgt * p.y * p.y);
        atomicAdd(&wo[6 * r + 1], wgt * p.y * p.z);
        atomicAdd(&wo[6 * r + 2], wgt * p.y * p.w);
        atomicAdd(&wo[6 * r + 3], wgt * p.z * p.z);
        atomicAdd(&wo[6 * r + 4], wgt * p.z * p.w);
        atomicAdd(&wo[6 * r + 5], wgt * p.w * p.w);
      }
}

__global__ void k_finalize(const Hdr* __restrict__ h,
                           const float* __restrict__ wsum,
                           const float* __restrict__ wp,
                           const float* __restrict__ wo,
                           float* __restrict__ out_mu,
                           float* __restrict__ out_R, int n) {
  int i = blockIdx.x * 256 + threadIdx.x;
  if (i >= n) return;
  float ws = wsum[i];
  bool ok = (i < h->M) && (ws > 0.0f);
  float* mu_o = out_mu + (size_t)i * 4;
  float* R_o = out_R + (size_t)i * 9;
  if (!ok) {
    mu_o[0] = mu_o[1] = mu_o[2] = mu_o[3] = 0.0f;
    #pragma unroll
    for (int k = 0; k < 9; ++k) R_o[k] = 0.0f;
    return;
  }
  float mu0 = wp[4 * i + 0] / ws;
  float mu1 = wp[4 * i + 1] / ws;
  float mu2 = wp[4 * i + 2] / ws;
  float mu3 = wp[4 * i + 3] / ws;
  float A[3][3];
  A[0][0] = wo[6 * i + 0] / ws - mu1 * mu1;
  A[0][1] = A[1][0] = wo[6 * i + 1] / ws - mu1 * mu2;
  A[0][2] = A[2][0] = wo[6 * i + 2] / ws - mu1 * mu3;
  A[1][1] = wo[6 * i + 3] / ws - mu2 * mu2;
  A[1][2] = A[2][1] = wo[6 * i + 4] / ws - mu2 * mu3;
  A[2][2] = wo[6 * i + 5] / ws - mu3 * mu3;

  float V[3][3] = {{1.f, 0.f, 0.f}, {0.f, 1.f, 0.f}, {0.f, 0.f, 1.f}};
  for (int sweep = 0; sweep < 8; ++sweep) {
    #pragma unroll
    for (int pi = 0; pi < 3; ++pi) {
      int p = (pi == 2) ? 1 : 0;
      int q = (pi == 0) ? 1 : 2;
      float apq = A[p][q];
      if (apq == 0.0f) continue;
      float app = A[p][p], aqq = A[q][q];
      float theta = (aqq - app) / (2.0f * apq);
      float t = 1.0f / (fabsf(theta) + sqrtf(theta * theta + 1.0f));
      if (theta < 0.0f) t = -t;
      float cth = 1.0f / sqrtf(t * t + 1.0f);
      float sth = t * cth;
      A[p][p] = app - t * apq;
      A[q][q] = aqq + t * apq;
      A[p][q] = A[q][p] = 0.0f;
      int k = 3 - p - q;
      float akp = A[k][p], akq = A[k][q];
      A[k][p] = A[p][k] = cth * akp - sth * akq;
      A[k][q] = A[q][k] = sth * akp + cth * akq;
      #pragma unroll
      for (int r = 0; r < 3; ++r) {
        float vp = V[r][p], vq = V[r][q];
        V[r][p] = cth * vp - sth * vq;
        V[r][q] = sth * vp + cth * vq;
      }
    }
  }
  float l[3] = {A[0][0], A[1][1], A[2][2]};
  float a[3] = {fabsf(l[0]), fabsf(l[1]), fabsf(l[2])};
  int idx[3] = {0, 1, 2};
  if (a[idx[0]] < a[idx[1]]) { int t = idx[0]; idx[0] = idx[1]; idx[1] = t; }
  if (a[idx[1]] < a[idx[2]]) { int t = idx[1]; idx[1] = idx[2]; idx[2] = t; }
  if (a[idx[0]] < a[idx[1]]) { int t = idx[0]; idx[0] = idx[1]; idx[1] = t; }
  float S0 = fmaxf(sqrtf(a[idx[0]]), 1e-6f);
  float S1 = fmaxf(sqrtf(a[idx[1]]), 1e-6f);
  float S2 = fmaxf(sqrtf(a[idx[2]]), 1e-6f);
  float U[3][3];
  #pragma unroll
  for (int r = 0; r < 3; ++r) {
    U[r][0] = V[r][idx[0]];
    U[r][1] = V[r][idx[1]];
    U[r][2] = V[r][idx[2]];
  }
  float det = U[0][0] * (U[1][1] * U[2][2] - U[1][2] * U[2][1])
            - U[0][1] * (U[1][0] * U[2][2] - U[1][2] * U[2][0])
            + U[0][2] * (U[1][0] * U[2][1] - U[1][1] * U[2][0]);
  float f2 = (det < 0.0f) ? -1.0f : 1.0f;
  mu_o[0] = mu0; mu_o[1] = mu1; mu_o[2] = mu2; mu_o[3] = mu3;
  R_o[0] = U[0][0] * S0; R_o[1] = U[0][1] * S1; R_o[2] = U[0][2] * S2 * f2;
  R_o[3] = U[1][0] * S0; R_o[4] = U[1][1] * S1; R_o[5] = U[1][2] * S2 * f2;
  R_o[6] = U[2][0] * S0; R_o[7] = U[2][1] * S1; R_o[8] = U[2][2] * S2 * f2;
}

extern "C" void kernel_launch(void* const* d_in, const int* in_sizes, int n_in,
                              void* d_out, int out_size, void* d_ws,
                              size_t ws_size, hipStream_t stream) {
  const float4* pts = (const float4*)d_in[0];
  int n = in_sizes[0] / 4;
  float* out = (float*)d_out;
  float* outR = out + (size_t)4 * n;

  char* ws = (char*)d_ws;
  Hdr* hdr = (Hdr*)ws;
  size_t off = 256;
  unsigned* bm = (unsigned*)(ws + off);          off += (size_t)WMAX * 4;
  unsigned short* rank16 = (unsigned short*)(ws + off); off += (size_t)WMAX * 2;
  unsigned* part = (unsigned*)(ws + off);        off += (size_t)24576 * 4;
  float* acc = (float*)(ws + off);
  float* wsum = acc;                 // n
  float* wp = acc + n;               // 4n
  float* wo = acc + 5 * (size_t)n;   // 6n
  size_t needed = off + (size_t)n * 11 * 4;
  if (ws_size < needed) return;

  // hdr init via memset: umin=0xFF..., umax + rest = 0
  hipMemsetAsync(hdr, 0xFF, 16, stream);
  hipMemsetAsync((char*)hdr + 16, 0x00, sizeof(Hdr) - 16, stream);
  hipMemsetAsync(bm, 0, (size_t)WMAX * 4, stream);
  hipMemsetAsync(acc, 0, (size_t)n * 11 * 4, stream);

  int nb = (n + 255) / 256;
  k_minmax<<<64, 256, 0, stream>>>(pts, n, hdr);
  k_prep<<<1, 64, 0, stream>>>(hdr);
  k_mark<<<nb, 256, 0, stream>>>(pts, n, hdr, bm);
  k_scanA<<<PBLK, 256, 0, stream>>>(bm, rank16, part);
  k_scanB<<<1, 256, 0, stream>>>(part, hdr);
  k_scatter<<<nb, 256, 0, stream>>>(pts, n, hdr, bm, rank16, part, wsum, wp, wo);
  k_finalize<<<nb, 256, 0, stream>>>(hdr, wsum, wp, wo, out, outR, n);
}

// Round 3
// 268.920 us; speedup vs baseline: 2.4511x; 1.2295x over previous
//
#include <hip/hip_runtime.h>
#include <stdint.h>

// ---------------------------------------------------------------------------
// PrimitiveFitting: voxel-hash primitive fitting (mu + scaled-eigvec R).
//
// R2 post-mortem: scatter was exec-mask-wasted (93% of wave-iterations ran the
// 11-atomic block with ~2 active lanes); scanB was a 83x serial single-block
// scan; scanA was 21k tiny blocks. Fixes:
//   - scatter: LDS hit-compaction, drain with full lanes active
//   - scanA: 2048 words/block (uint4 loads, ushort8 rank writes)
//   - scanB: single LDS scan (2638 partials)
//   - minmax: partials to workspace, reduced inside k_prep (no atomics)
// ---------------------------------------------------------------------------

#define WMAX  5402624u        // bitmap words = 2638 * 2048  (>= 10*258^3 / 32)
#define PBLK  2638            // scanA superblocks (2048 words = 65536 bits each)
#define CHUNK 11              // ceil(PBLK / 256)
#define HCAP  2048            // LDS hit buffer entries (expected ~280/block)

struct Hdr {
  float pc_min[4];
  int   dims[4];
  int   K, M;
};

__device__ __forceinline__ unsigned fkey_map(float f) {
  unsigned u = __float_as_uint(f);
  return (u & 0x80000000u) ? ~u : (u | 0x80000000u);
}
__device__ __forceinline__ float fkey_unmap(unsigned u) {
  unsigned b = (u & 0x80000000u) ? (u ^ 0x80000000u) : ~u;
  return __uint_as_float(b);
}

// 256 blocks; block LDS reduce; write 8 mapped-uint partials per block.
__global__ void k_minmax(const float4* __restrict__ pts, int n,
                         unsigned* __restrict__ mmpart) {
  __shared__ unsigned smem[4 * 8];
  float mn[4] = { INFINITY,  INFINITY,  INFINITY,  INFINITY};
  float mx[4] = {-INFINITY, -INFINITY, -INFINITY, -INFINITY};
  for (int i = blockIdx.x * blockDim.x + threadIdx.x; i < n;
       i += gridDim.x * blockDim.x) {
    float4 p = pts[i];
    mn[0] = fminf(mn[0], p.x); mx[0] = fmaxf(mx[0], p.x);
    mn[1] = fminf(mn[1], p.y); mx[1] = fmaxf(mx[1], p.y);
    mn[2] = fminf(mn[2], p.z); mx[2] = fmaxf(mx[2], p.z);
    mn[3] = fminf(mn[3], p.w); mx[3] = fmaxf(mx[3], p.w);
  }
  #pragma unroll
  for (int off = 32; off > 0; off >>= 1) {
    #pragma unroll
    for (int c = 0; c < 4; ++c) {
      mn[c] = fminf(mn[c], __shfl_down(mn[c], off));
      mx[c] = fmaxf(mx[c], __shfl_down(mx[c], off));
    }
  }
  int wave = threadIdx.x >> 6;
  if ((threadIdx.x & 63) == 0) {
    #pragma unroll
    for (int c = 0; c < 4; ++c) {
      smem[wave * 8 + c]     = fkey_map(mn[c]);
      smem[wave * 8 + 4 + c] = fkey_map(mx[c]);
    }
  }
  __syncthreads();
  int t = threadIdx.x;
  if (t < 8) {
    unsigned u = smem[t];
    #pragma unroll
    for (int w = 1; w < 4; ++w)
      u = (t < 4) ? min(u, smem[w * 8 + t]) : max(u, smem[w * 8 + t]);
    mmpart[blockIdx.x * 8 + t] = u;
  }
}

// reduce 256x8 partials, then compute pc_min / dims / K (bitwise == numpy).
__global__ void k_prep(const unsigned* __restrict__ mmpart, Hdr* h) {
  __shared__ unsigned s[256 * 8];
  int t = threadIdx.x;
  #pragma unroll
  for (int c = 0; c < 8; ++c) s[t * 8 + c] = mmpart[t * 8 + c];
  __syncthreads();
  for (int off = 128; off > 0; off >>= 1) {
    if (t < off) {
      #pragma unroll
      for (int c = 0; c < 4; ++c)
        s[t * 8 + c] = min(s[t * 8 + c], s[(t + off) * 8 + c]);
      #pragma unroll
      for (int c = 4; c < 8; ++c)
        s[t * 8 + c] = max(s[t * 8 + c], s[(t + off) * 8 + c]);
    }
    __syncthreads();
  }
  if (t == 0) {
    const float vs[4] = {1.0f, 0.4f, 0.4f, 0.4f};
    int dims[4];
    #pragma unroll
    for (int c = 0; c < 4; ++c) {
      float mn = fkey_unmap(s[c]);
      float mx = fkey_unmap(s[4 + c]);
      float pmin = mn - vs[c] * 2.0f;
      float pmax = mx + vs[c] * 2.0f;
      h->pc_min[c] = pmin;
      dims[c] = (int)rintf((pmax - pmin) / vs[c]) + 3;  // np.round half-even
      h->dims[c] = dims[c];
    }
    int K = dims[0];
    #pragma unroll
    for (int c = 1; c < 4; ++c) K *= dims[c];
    h->K = K;
  }
}

__device__ __forceinline__ void point_coors(float4 p, const Hdr* __restrict__ h,
                                            int c[4]) {
  // Must match numpy bitwise: f32 subtract, IEEE f32 divide, rint (half-even).
  c[0] = (int)rintf((p.x - h->pc_min[0]) / 1.0f) + 1;
  c[1] = (int)rintf((p.y - h->pc_min[1]) / 0.4f) + 1;
  c[2] = (int)rintf((p.z - h->pc_min[2]) / 0.4f) + 1;
  c[3] = (int)rintf((p.w - h->pc_min[3]) / 0.4f) + 1;
}

__global__ void k_mark(const float4* __restrict__ pts, int n,
                       const Hdr* __restrict__ h, unsigned* __restrict__ bm) {
  int i = blockIdx.x * 256 + threadIdx.x;
  if (i >= n) return;
  float4 p = pts[i];
  int c[4]; point_coors(p, h, c);
  int key = ((c[0] * h->dims[1] + c[1]) * h->dims[2] + c[2]) * h->dims[3] + c[3];
  unsigned uk = (unsigned)key;
  if (uk >= WMAX * 32u) return;   // safety (never taken for valid data)
  atomicOr(&bm[uk >> 5], 1u << (uk & 31u));
}

// 2048 words / block: per-thread 8-word popcount prefix + one LDS scan.
// rank16[w] = exclusive bit-prefix within the 65536-bit superblock (fits u16).
__global__ void k_scanA(const unsigned* __restrict__ bm,
                        unsigned short* __restrict__ rank16,
                        unsigned* __restrict__ part) {
  __shared__ unsigned s[256];
  int t = threadIdx.x;
  size_t base = (size_t)blockIdx.x * 2048 + (size_t)t * 8;
  uint4 a = *(const uint4*)(bm + base);
  uint4 b = *(const uint4*)(bm + base + 4);
  unsigned pc[8] = {(unsigned)__popc(a.x), (unsigned)__popc(a.y),
                    (unsigned)__popc(a.z), (unsigned)__popc(a.w),
                    (unsigned)__popc(b.x), (unsigned)__popc(b.y),
                    (unsigned)__popc(b.z), (unsigned)__popc(b.w)};
  unsigned sum = 0;
  #pragma unroll
  for (int k = 0; k < 8; ++k) sum += pc[k];
  s[t] = sum; __syncthreads();
  for (int off = 1; off < 256; off <<= 1) {
    unsigned v = (t >= off) ? s[t - off] : 0u;
    __syncthreads();
    s[t] += v;
    __syncthreads();
  }
  unsigned run = s[t] - sum;
  unsigned r[8];
  #pragma unroll
  for (int k = 0; k < 8; ++k) { r[k] = run; run += pc[k]; }
  uint4 o;
  o.x = (r[0] & 0xFFFFu) | (r[1] << 16);
  o.y = (r[2] & 0xFFFFu) | (r[3] << 16);
  o.z = (r[4] & 0xFFFFu) | (r[5] << 16);
  o.w = (r[6] & 0xFFFFu) | (r[7] << 16);
  *(uint4*)(rank16 + base) = o;
  if (t == 255) part[blockIdx.x] = s[255];
}

// single block: exclusive scan of 2638 superblock totals.
__global__ void k_scanB(unsigned* __restrict__ part, Hdr* h) {
  __shared__ unsigned s[256];
  int t = threadIdx.x;
  int lo = t * CHUNK;
  unsigned local[CHUNK];
  unsigned sum = 0;
  #pragma unroll
  for (int k = 0; k < CHUNK; ++k) {
    int j = lo + k;
    local[k] = (j < PBLK) ? part[j] : 0u;
    sum += local[k];
  }
  s[t] = sum; __syncthreads();
  for (int off = 1; off < 256; off <<= 1) {
    unsigned v = (t >= off) ? s[t - off] : 0u;
    __syncthreads();
    s[t] += v;
    __syncthreads();
  }
  unsigned run = s[t] - sum;
  #pragma unroll
  for (int k = 0; k < CHUNK; ++k) {
    int j = lo + k;
    if (j < PBLK) part[j] = run;
    run += local[k];
  }
  if (t == 255) h->M = (int)s[255];
}

// Probe 27 neighbors -> compact hits (i, r, w) into LDS -> drain with full
// lanes active (R2 fix: was 93% of wave-iters running 11 atomics on ~2 lanes).
__global__ void k_scatter(const float4* __restrict__ pts, int n,
                          const Hdr* __restrict__ h,
                          const unsigned* __restrict__ bm,
                          const unsigned short* __restrict__ rank16,
                          const unsigned* __restrict__ part,
                          float* __restrict__ wsum, float* __restrict__ wp,
                          float* __restrict__ wo) {
  __shared__ int s_cnt;
  __shared__ int   s_i[HCAP];
  __shared__ int   s_r[HCAP];
  __shared__ float s_w[HCAP];
  if (threadIdx.x == 0) s_cnt = 0;
  __syncthreads();

  int i = blockIdx.x * 256 + threadIdx.x;
  const float gg = 0.4f * 0.4f;
  const float decay2 = (gg + gg + gg) * 0.25f;   // bitwise == ref

  if (i < n) {
    float4 p = pts[i];
    int c[4]; point_coors(p, h, c);
    int d1 = h->dims[1], d2 = h->dims[2], d3 = h->dims[3];
    float m1 = h->pc_min[1], m2 = h->pc_min[2], m3 = h->pc_min[3];
    int base0 = c[0] * d1;
    for (int dx = -1; dx <= 1; ++dx)
      for (int dy = -1; dy <= 1; ++dy)
        for (int dz = -1; dz <= 1; ++dz) {
          int n1 = c[1] + dx, n2 = c[2] + dy, n3 = c[3] + dz;
          int key = ((base0 + n1) * d2 + n2) * d3 + n3;
          unsigned uk = (unsigned)key;
          if (uk >= WMAX * 32u) continue;          // safety
          unsigned word = bm[uk >> 5];
          unsigned bit = uk & 31u;
          if (!((word >> bit) & 1u)) continue;     // unoccupied neighbor
          int r = (int)(part[uk >> 16] + (unsigned)rank16[uk >> 5] +
                        __popc(word & ((1u << bit) - 1u)));
          float cx = (float)(n1 - 1) * 0.4f + m1;
          float cy = (float)(n2 - 1) * 0.4f + m2;
          float cz = (float)(n3 - 1) * 0.4f + m3;
          float ex = p.y - cx, ey = p.z - cy, ez = p.w - cz;
          float dd = ex * ex + ey * ey + ez * ez;
          float wgt = expf(-dd / decay2);
          int pos = atomicAdd(&s_cnt, 1);
          if (pos < HCAP) {
            s_i[pos] = i; s_r[pos] = r; s_w[pos] = wgt;
          } else {                                  // overflow fallback (rare)
            atomicAdd(&wsum[r], wgt);
            atomicAdd(&wp[4 * r + 0], wgt * p.x);
            atomicAdd(&wp[4 * r + 1], wgt * p.y);
            atomicAdd(&wp[4 * r + 2], wgt * p.z);
            atomicAdd(&wp[4 * r + 3], wgt * p.w);
            atomicAdd(&wo[6 * r + 0], wgt * p.y * p.y);
            atomicAdd(&wo[6 * r + 1], wgt * p.y * p.z);
            atomicAdd(&wo[6 * r + 2], wgt * p.y * p.w);
            atomicAdd(&wo[6 * r + 3], wgt * p.z * p.z);
            atomicAdd(&wo[6 * r + 4], wgt * p.z * p.w);
            atomicAdd(&wo[6 * r + 5], wgt * p.w * p.w);
          }
        }
  }
  __syncthreads();
  int cnt = min(s_cnt, HCAP);
  for (int j = threadIdx.x; j < cnt; j += 256) {
    float4 q = pts[s_i[j]];          // L1-resident (block just read it)
    int r = s_r[j];
    float wgt = s_w[j];
    atomicAdd(&wsum[r], wgt);
    atomicAdd(&wp[4 * r + 0], wgt * q.x);
    atomicAdd(&wp[4 * r + 1], wgt * q.y);
    atomicAdd(&wp[4 * r + 2], wgt * q.z);
    atomicAdd(&wp[4 * r + 3], wgt * q.w);
    atomicAdd(&wo[6 * r + 0], wgt * q.y * q.y);
    atomicAdd(&wo[6 * r + 1], wgt * q.y * q.z);
    atomicAdd(&wo[6 * r + 2], wgt * q.y * q.w);
    atomicAdd(&wo[6 * r + 3], wgt * q.z * q.z);
    atomicAdd(&wo[6 * r + 4], wgt * q.z * q.w);
    atomicAdd(&wo[6 * r + 5], wgt * q.w * q.w);
  }
}

__global__ void k_finalize(const Hdr* __restrict__ h,
                           const float* __restrict__ wsum,
                           const float* __restrict__ wp,
                           const float* __restrict__ wo,
                           float* __restrict__ out_mu,
                           float* __restrict__ out_R, int n) {
  int i = blockIdx.x * 256 + threadIdx.x;
  if (i >= n) return;
  float ws = wsum[i];
  bool ok = (i < h->M) && (ws > 0.0f);
  float* mu_o = out_mu + (size_t)i * 4;
  float* R_o = out_R + (size_t)i * 9;
  if (!ok) {
    mu_o[0] = mu_o[1] = mu_o[2] = mu_o[3] = 0.0f;
    #pragma unroll
    for (int k = 0; k < 9; ++k) R_o[k] = 0.0f;
    return;
  }
  float mu0 = wp[4 * i + 0] / ws;
  float mu1 = wp[4 * i + 1] / ws;
  float mu2 = wp[4 * i + 2] / ws;
  float mu3 = wp[4 * i + 3] / ws;
  float A[3][3];
  A[0][0] = wo[6 * i + 0] / ws - mu1 * mu1;
  A[0][1] = A[1][0] = wo[6 * i + 1] / ws - mu1 * mu2;
  A[0][2] = A[2][0] = wo[6 * i + 2] / ws - mu1 * mu3;
  A[1][1] = wo[6 * i + 3] / ws - mu2 * mu2;
  A[1][2] = A[2][1] = wo[6 * i + 4] / ws - mu2 * mu3;
  A[2][2] = wo[6 * i + 5] / ws - mu3 * mu3;

  float V[3][3] = {{1.f, 0.f, 0.f}, {0.f, 1.f, 0.f}, {0.f, 0.f, 1.f}};
  for (int sweep = 0; sweep < 8; ++sweep) {
    #pragma unroll
    for (int pi = 0; pi < 3; ++pi) {
      int p = (pi == 2) ? 1 : 0;
      int q = (pi == 0) ? 1 : 2;
      float apq = A[p][q];
      if (apq == 0.0f) continue;
      float app = A[p][p], aqq = A[q][q];
      float theta = (aqq - app) / (2.0f * apq);
      float t = 1.0f / (fabsf(theta) + sqrtf(theta * theta + 1.0f));
      if (theta < 0.0f) t = -t;
      float cth = 1.0f / sqrtf(t * t + 1.0f);
      float sth = t * cth;
      A[p][p] = app - t * apq;
      A[q][q] = aqq + t * apq;
      A[p][q] = A[q][p] = 0.0f;
      int k = 3 - p - q;
      float akp = A[k][p], akq = A[k][q];
      A[k][p] = A[p][k] = cth * akp - sth * akq;
      A[k][q] = A[q][k] = sth * akp + cth * akq;
      #pragma unroll
      for (int r = 0; r < 3; ++r) {
        float vp = V[r][p], vq = V[r][q];
        V[r][p] = cth * vp - sth * vq;
        V[r][q] = sth * vp + cth * vq;
      }
    }
  }
  float l[3] = {A[0][0], A[1][1], A[2][2]};
  float a[3] = {fabsf(l[0]), fabsf(l[1]), fabsf(l[2])};
  int idx[3] = {0, 1, 2};
  if (a[idx[0]] < a[idx[1]]) { int t = idx[0]; idx[0] = idx[1]; idx[1] = t; }
  if (a[idx[1]] < a[idx[2]]) { int t = idx[1]; idx[1] = idx[2]; idx[2] = t; }
  if (a[idx[0]] < a[idx[1]]) { int t = idx[0]; idx[0] = idx[1]; idx[1] = t; }
  float S0 = fmaxf(sqrtf(a[idx[0]]), 1e-6f);
  float S1 = fmaxf(sqrtf(a[idx[1]]), 1e-6f);
  float S2 = fmaxf(sqrtf(a[idx[2]]), 1e-6f);
  float U[3][3];
  #pragma unroll
  for (int r = 0; r < 3; ++r) {
    U[r][0] = V[r][idx[0]];
    U[r][1] = V[r][idx[1]];
    U[r][2] = V[r][idx[2]];
  }
  float det = U[0][0] * (U[1][1] * U[2][2] - U[1][2] * U[2][1])
            - U[0][1] * (U[1][0] * U[2][2] - U[1][2] * U[2][0])
            + U[0][2] * (U[1][0] * U[2][1] - U[1][1] * U[2][0]);
  float f2 = (det < 0.0f) ? -1.0f : 1.0f;
  mu_o[0] = mu0; mu_o[1] = mu1; mu_o[2] = mu2; mu_o[3] = mu3;
  R_o[0] = U[0][0] * S0; R_o[1] = U[0][1] * S1; R_o[2] = U[0][2] * S2 * f2;
  R_o[3] = U[1][0] * S0; R_o[4] = U[1][1] * S1; R_o[5] = U[1][2] * S2 * f2;
  R_o[6] = U[2][0] * S0; R_o[7] = U[2][1] * S1; R_o[8] = U[2][2] * S2 * f2;
}

extern "C" void kernel_launch(void* const* d_in, const int* in_sizes, int n_in,
                              void* d_out, int out_size, void* d_ws,
                              size_t ws_size, hipStream_t stream) {
  const float4* pts = (const float4*)d_in[0];
  int n = in_sizes[0] / 4;
  float* out = (float*)d_out;
  float* outR = out + (size_t)4 * n;

  char* ws = (char*)d_ws;
  Hdr* hdr = (Hdr*)ws;
  size_t off = 256;
  unsigned* mmpart = (unsigned*)(ws + off);      off += 256 * 8 * 4;
  unsigned* bm = (unsigned*)(ws + off);          off += (size_t)WMAX * 4;
  unsigned short* rank16 = (unsigned short*)(ws + off); off += (size_t)WMAX * 2;
  unsigned* part = (unsigned*)(ws + off);        off += 4096 * 4;
  float* acc = (float*)(ws + off);
  float* wsum = acc;                 // n
  float* wp = acc + n;               // 4n
  float* wo = acc + 5 * (size_t)n;   // 6n
  size_t needed = off + (size_t)n * 11 * 4;
  if (ws_size < needed) return;

  hipMemsetAsync(bm, 0, (size_t)WMAX * 4, stream);
  hipMemsetAsync(acc, 0, (size_t)n * 11 * 4, stream);

  int nb = (n + 255) / 256;
  k_minmax<<<256, 256, 0, stream>>>(pts, n, mmpart);
  k_prep<<<1, 256, 0, stream>>>(mmpart, hdr);
  k_mark<<<nb, 256, 0, stream>>>(pts, n, hdr, bm);
  k_scanA<<<PBLK, 256, 0, stream>>>(bm, rank16, part);
  k_scanB<<<1, 256, 0, stream>>>(part, hdr);
  k_scatter<<<nb, 256, 0, stream>>>(pts, n, hdr, bm, rank16, part, wsum, wp, wo);
  k_finalize<<<nb, 256, 0, stream>>>(hdr, wsum, wp, wo, out, outR, n);
}

// Round 4
// 194.001 us; speedup vs baseline: 3.3976x; 1.3862x over previous
//
#include <hip/hip_runtime.h>
#include <stdint.h>

// ---------------------------------------------------------------------------
// PrimitiveFitting: voxel-hash primitive fitting (mu + scaled-eigvec R).
//
// R3 post-mortem: scatter is bound by device-scope atomic fabric transactions
// (74MB WRITE = 2.39M atomics x 32B RMW past non-coherent L2) + 5.4M random
// 4B bitmap probes (54MB FETCH). Fixes this round:
//   - probe: dz-triple = 3 consecutive bits -> 9 word-loads per point (not 27)
//   - two-phase scatter: probe appends (i,r,w) hit list + 1 count-atomic/hit;
//     drain does plain float4 stores for single-contributor voxels (~95%),
//     atomicAdd only for shared voxels (~5%)
//   - acc is 12-float AoS (wsum, wp[4], wo[6], cnt) -> 48B/voxel locality
// ---------------------------------------------------------------------------

#define WMAX   5402624u       // bitmap words = 2638 * 2048  (>= 10*258^3 / 32)
#define PBLK   2638           // scanA superblocks (2048 words = 65536 bits)
#define CHUNK  11             // ceil(PBLK / 256)
#define HCAP   1024           // LDS staging entries / block (expected ~280)
#define HITCAP 786432         // global hit list capacity (expected ~216k)

struct Hdr {
  float pc_min[4];
  int   dims[4];
  int   K, M;
};

__device__ __forceinline__ unsigned fkey_map(float f) {
  unsigned u = __float_as_uint(f);
  return (u & 0x80000000u) ? ~u : (u | 0x80000000u);
}
__device__ __forceinline__ float fkey_unmap(unsigned u) {
  unsigned b = (u & 0x80000000u) ? (u ^ 0x80000000u) : ~u;
  return __uint_as_float(b);
}

__global__ void k_minmax(const float4* __restrict__ pts, int n,
                         unsigned* __restrict__ mmpart) {
  __shared__ unsigned smem[4 * 8];
  float mn[4] = { INFINITY,  INFINITY,  INFINITY,  INFINITY};
  float mx[4] = {-INFINITY, -INFINITY, -INFINITY, -INFINITY};
  for (int i = blockIdx.x * blockDim.x + threadIdx.x; i < n;
       i += gridDim.x * blockDim.x) {
    float4 p = pts[i];
    mn[0] = fminf(mn[0], p.x); mx[0] = fmaxf(mx[0], p.x);
    mn[1] = fminf(mn[1], p.y); mx[1] = fmaxf(mx[1], p.y);
    mn[2] = fminf(mn[2], p.z); mx[2] = fmaxf(mx[2], p.z);
    mn[3] = fminf(mn[3], p.w); mx[3] = fmaxf(mx[3], p.w);
  }
  #pragma unroll
  for (int off = 32; off > 0; off >>= 1) {
    #pragma unroll
    for (int c = 0; c < 4; ++c) {
      mn[c] = fminf(mn[c], __shfl_down(mn[c], off));
      mx[c] = fmaxf(mx[c], __shfl_down(mx[c], off));
    }
  }
  int wave = threadIdx.x >> 6;
  if ((threadIdx.x & 63) == 0) {
    #pragma unroll
    for (int c = 0; c < 4; ++c) {
      smem[wave * 8 + c]     = fkey_map(mn[c]);
      smem[wave * 8 + 4 + c] = fkey_map(mx[c]);
    }
  }
  __syncthreads();
  int t = threadIdx.x;
  if (t < 8) {
    unsigned u = smem[t];
    #pragma unroll
    for (int w = 1; w < 4; ++w)
      u = (t < 4) ? min(u, smem[w * 8 + t]) : max(u, smem[w * 8 + t]);
    mmpart[blockIdx.x * 8 + t] = u;
  }
}

__global__ void k_prep(const unsigned* __restrict__ mmpart, Hdr* h) {
  __shared__ unsigned s[256 * 8];
  int t = threadIdx.x;
  #pragma unroll
  for (int c = 0; c < 8; ++c) s[t * 8 + c] = mmpart[t * 8 + c];
  __syncthreads();
  for (int off = 128; off > 0; off >>= 1) {
    if (t < off) {
      #pragma unroll
      for (int c = 0; c < 4; ++c)
        s[t * 8 + c] = min(s[t * 8 + c], s[(t + off) * 8 + c]);
      #pragma unroll
      for (int c = 4; c < 8; ++c)
        s[t * 8 + c] = max(s[t * 8 + c], s[(t + off) * 8 + c]);
    }
    __syncthreads();
  }
  if (t == 0) {
    const float vs[4] = {1.0f, 0.4f, 0.4f, 0.4f};
    int dims[4];
    #pragma unroll
    for (int c = 0; c < 4; ++c) {
      float mn = fkey_unmap(s[c]);
      float mx = fkey_unmap(s[4 + c]);
      float pmin = mn - vs[c] * 2.0f;
      float pmax = mx + vs[c] * 2.0f;
      h->pc_min[c] = pmin;
      dims[c] = (int)rintf((pmax - pmin) / vs[c]) + 3;  // np.round half-even
      h->dims[c] = dims[c];
    }
    int K = dims[0];
    #pragma unroll
    for (int c = 1; c < 4; ++c) K *= dims[c];
    h->K = K;
  }
}

__device__ __forceinline__ void point_coors(float4 p, const Hdr* __restrict__ h,
                                            int c[4]) {
  // Must match numpy bitwise: f32 subtract, IEEE f32 divide, rint (half-even).
  c[0] = (int)rintf((p.x - h->pc_min[0]) / 1.0f) + 1;
  c[1] = (int)rintf((p.y - h->pc_min[1]) / 0.4f) + 1;
  c[2] = (int)rintf((p.z - h->pc_min[2]) / 0.4f) + 1;
  c[3] = (int)rintf((p.w - h->pc_min[3]) / 0.4f) + 1;
}

__global__ void k_mark(const float4* __restrict__ pts, int n,
                       const Hdr* __restrict__ h, unsigned* __restrict__ bm) {
  int i = blockIdx.x * 256 + threadIdx.x;
  if (i >= n) return;
  float4 p = pts[i];
  int c[4]; point_coors(p, h, c);
  int key = ((c[0] * h->dims[1] + c[1]) * h->dims[2] + c[2]) * h->dims[3] + c[3];
  unsigned uk = (unsigned)key;
  if (uk >= WMAX * 32u) return;   // safety (never taken for valid data)
  atomicOr(&bm[uk >> 5], 1u << (uk & 31u));
}

// 2048 words / block: per-thread 8-word popcount prefix + one LDS scan.
__global__ void k_scanA(const unsigned* __restrict__ bm,
                        unsigned short* __restrict__ rank16,
                        unsigned* __restrict__ part) {
  __shared__ unsigned s[256];
  int t = threadIdx.x;
  size_t base = (size_t)blockIdx.x * 2048 + (size_t)t * 8;
  uint4 a = *(const uint4*)(bm + base);
  uint4 b = *(const uint4*)(bm + base + 4);
  unsigned pc[8] = {(unsigned)__popc(a.x), (unsigned)__popc(a.y),
                    (unsigned)__popc(a.z), (unsigned)__popc(a.w),
                    (unsigned)__popc(b.x), (unsigned)__popc(b.y),
                    (unsigned)__popc(b.z), (unsigned)__popc(b.w)};
  unsigned sum = 0;
  #pragma unroll
  for (int k = 0; k < 8; ++k) sum += pc[k];
  s[t] = sum; __syncthreads();
  for (int off = 1; off < 256; off <<= 1) {
    unsigned v = (t >= off) ? s[t - off] : 0u;
    __syncthreads();
    s[t] += v;
    __syncthreads();
  }
  unsigned run = s[t] - sum;
  unsigned r[8];
  #pragma unroll
  for (int k = 0; k < 8; ++k) { r[k] = run; run += pc[k]; }
  uint4 o;
  o.x = (r[0] & 0xFFFFu) | (r[1] << 16);
  o.y = (r[2] & 0xFFFFu) | (r[3] << 16);
  o.z = (r[4] & 0xFFFFu) | (r[5] << 16);
  o.w = (r[6] & 0xFFFFu) | (r[7] << 16);
  *(uint4*)(rank16 + base) = o;
  if (t == 255) part[blockIdx.x] = s[255];
}

__global__ void k_scanB(unsigned* __restrict__ part, Hdr* h) {
  __shared__ unsigned s[256];
  int t = threadIdx.x;
  int lo = t * CHUNK;
  unsigned local[CHUNK];
  unsigned sum = 0;
  #pragma unroll
  for (int k = 0; k < CHUNK; ++k) {
    int j = lo + k;
    local[k] = (j < PBLK) ? part[j] : 0u;
    sum += local[k];
  }
  s[t] = sum; __syncthreads();
  for (int off = 1; off < 256; off <<= 1) {
    unsigned v = (t >= off) ? s[t - off] : 0u;
    __syncthreads();
    s[t] += v;
    __syncthreads();
  }
  unsigned run = s[t] - sum;
  #pragma unroll
  for (int k = 0; k < CHUNK; ++k) {
    int j = lo + k;
    if (j < PBLK) part[j] = run;
    run += local[k];
  }
  if (t == 255) h->M = (int)s[255];
}

__device__ __forceinline__ void direct_accum(float* __restrict__ acc, int r,
                                             float wgt, float4 p) {
  float* a = acc + (size_t)r * 12;
  atomicAdd((unsigned*)(a + 11), 1u);            // contributor count
  atomicAdd(a + 0, wgt);
  atomicAdd(a + 1, wgt * p.x);
  atomicAdd(a + 2, wgt * p.y);
  atomicAdd(a + 3, wgt * p.z);
  atomicAdd(a + 4, wgt * p.w);
  atomicAdd(a + 5, wgt * p.y * p.y);
  atomicAdd(a + 6, wgt * p.y * p.z);
  atomicAdd(a + 7, wgt * p.y * p.w);
  atomicAdd(a + 8, wgt * p.z * p.z);
  atomicAdd(a + 9, wgt * p.z * p.w);
  atomicAdd(a + 10, wgt * p.w * p.w);
}

// Phase 1: 9 word-probes per point (dz-triple = 3 consecutive bits);
// append hits (i,r,w) to global list; one count-atomic per hit.
__global__ void k_probe(const float4* __restrict__ pts, int n,
                        const Hdr* __restrict__ h,
                        const unsigned* __restrict__ bm,
                        const unsigned short* __restrict__ rank16,
                        const unsigned* __restrict__ part,
                        int* __restrict__ hit_i, int* __restrict__ hit_r,
                        float* __restrict__ hit_w,
                        unsigned* __restrict__ g_cnt,
                        float* __restrict__ acc) {
  __shared__ int s_cnt;
  __shared__ int s_base;
  __shared__ int   s_i[HCAP];
  __shared__ int   s_r[HCAP];
  __shared__ float s_w[HCAP];
  if (threadIdx.x == 0) s_cnt = 0;
  __syncthreads();

  int i = blockIdx.x * 256 + threadIdx.x;
  const float gg = 0.4f * 0.4f;
  const float decay2 = (gg + gg + gg) * 0.25f;   // bitwise == ref

  if (i < n) {
    float4 p = pts[i];
    int c[4]; point_coors(p, h, c);
    int d1 = h->dims[1], d2 = h->dims[2], d3 = h->dims[3];
    float m1 = h->pc_min[1], m2 = h->pc_min[2], m3 = h->pc_min[3];
    #pragma unroll
    for (int dx = -1; dx <= 1; ++dx) {
      #pragma unroll
      for (int dy = -1; dy <= 1; ++dy) {
        int n1 = c[1] + dx, n2 = c[2] + dy;
        int kc = ((c[0] * d1 + n1) * d2 + n2) * d3 + c[3];  // dz = 0
        unsigned k = (unsigned)kc;
        if (k < 1u || k + 1u >= WMAX * 32u) continue;       // safety
        unsigned w = k >> 5, b = k & 31u;
        unsigned cur = bm[w];
        unsigned tri;
        if (b == 0u)
          tri = (bm[w - 1] >> 31) | ((cur & 3u) << 1);
        else if (b == 31u)
          tri = ((cur >> 30) & 3u) | ((bm[w + 1] & 1u) << 2);
        else
          tri = (cur >> (b - 1)) & 7u;
        if (!tri) continue;
        #pragma unroll
        for (int j = 0; j < 3; ++j) {
          if (!((tri >> j) & 1u)) continue;
          unsigned kj = k + (unsigned)(j - 1);
          unsigned wj = kj >> 5, bj = kj & 31u;
          unsigned word = (wj == w) ? cur : bm[wj];
          int r = (int)(part[kj >> 16] + (unsigned)rank16[wj] +
                        __popc(word & ((1u << bj) - 1u)));
          int n3 = c[3] + (j - 1);
          float cx = (float)(n1 - 1) * 0.4f + m1;
          float cy = (float)(n2 - 1) * 0.4f + m2;
          float cz = (float)(n3 - 1) * 0.4f + m3;
          float ex = p.y - cx, ey = p.z - cy, ez = p.w - cz;
          float dd = ex * ex + ey * ey + ez * ez;
          float wgt = expf(-dd / decay2);
          int pos = atomicAdd(&s_cnt, 1);
          if (pos < HCAP) {
            s_i[pos] = i; s_r[pos] = r; s_w[pos] = wgt;
          } else {
            direct_accum(acc, r, wgt, p);        // LDS overflow (never normally)
          }
        }
      }
    }
  }
  __syncthreads();
  int cnt = min(s_cnt, HCAP);
  if (threadIdx.x == 0) s_base = (int)atomicAdd(g_cnt, (unsigned)cnt);
  __syncthreads();
  int base = s_base;
  for (int j = threadIdx.x; j < cnt; j += 256) {
    int gpos = base + j;
    int r = s_r[j];
    if (gpos < HITCAP) {
      hit_i[gpos] = s_i[j];
      hit_r[gpos] = r;
      hit_w[gpos] = s_w[j];
      atomicAdd((unsigned*)(acc + (size_t)r * 12 + 11), 1u);
    } else {
      direct_accum(acc, r, s_w[j], pts[s_i[j]]); // global overflow (never normally)
    }
  }
}

// Phase 2: single-contributor voxels (~95%) -> three plain float4 stores;
// shared voxels -> 11 atomicAdds.
__global__ void k_drain(const float4* __restrict__ pts,
                        const int* __restrict__ hit_i,
                        const int* __restrict__ hit_r,
                        const float* __restrict__ hit_w,
                        const unsigned* __restrict__ g_cnt,
                        float* __restrict__ acc) {
  int total = min((int)*g_cnt, HITCAP);
  for (int j = blockIdx.x * 256 + threadIdx.x; j < total;
       j += gridDim.x * 256) {
    int r = hit_r[j];
    float wgt = hit_w[j];
    float4 q = pts[hit_i[j]];
    float* a = acc + (size_t)r * 12;
    unsigned c = *(const unsigned*)(a + 11);
    if (c == 1u) {
      float4 v0 = {wgt, wgt * q.x, wgt * q.y, wgt * q.z};
      float4 v1 = {wgt * q.w, wgt * q.y * q.y, wgt * q.y * q.z,
                   wgt * q.y * q.w};
      float4 v2 = {wgt * q.z * q.z, wgt * q.z * q.w, wgt * q.w * q.w, 0.0f};
      float4* av = (float4*)a;
      av[0] = v0; av[1] = v1; av[2] = v2;
    } else {
      atomicAdd(a + 0, wgt);
      atomicAdd(a + 1, wgt * q.x);
      atomicAdd(a + 2, wgt * q.y);
      atomicAdd(a + 3, wgt * q.z);
      atomicAdd(a + 4, wgt * q.w);
      atomicAdd(a + 5, wgt * q.y * q.y);
      atomicAdd(a + 6, wgt * q.y * q.z);
      atomicAdd(a + 7, wgt * q.y * q.w);
      atomicAdd(a + 8, wgt * q.z * q.z);
      atomicAdd(a + 9, wgt * q.z * q.w);
      atomicAdd(a + 10, wgt * q.w * q.w);
    }
  }
}

__global__ void k_finalize(const Hdr* __restrict__ h,
                           const float* __restrict__ acc,
                           float* __restrict__ out_mu,
                           float* __restrict__ out_R, int n) {
  int i = blockIdx.x * 256 + threadIdx.x;
  if (i >= n) return;
  const float4* av = (const float4*)(acc + (size_t)i * 12);
  float4 v0 = av[0], v1 = av[1], v2 = av[2];
  float ws = v0.x;
  bool ok = (i < h->M) && (ws > 0.0f);
  float* mu_o = out_mu + (size_t)i * 4;
  float* R_o = out_R + (size_t)i * 9;
  if (!ok) {
    mu_o[0] = mu_o[1] = mu_o[2] = mu_o[3] = 0.0f;
    #pragma unroll
    for (int k = 0; k < 9; ++k) R_o[k] = 0.0f;
    return;
  }
  float mu0 = v0.y / ws;
  float mu1 = v0.z / ws;
  float mu2 = v0.w / ws;
  float mu3 = v1.x / ws;
  float A[3][3];
  A[0][0] = v1.y / ws - mu1 * mu1;
  A[0][1] = A[1][0] = v1.z / ws - mu1 * mu2;
  A[0][2] = A[2][0] = v1.w / ws - mu1 * mu3;
  A[1][1] = v2.x / ws - mu2 * mu2;
  A[1][2] = A[2][1] = v2.y / ws - mu2 * mu3;
  A[2][2] = v2.z / ws - mu3 * mu3;

  float V[3][3] = {{1.f, 0.f, 0.f}, {0.f, 1.f, 0.f}, {0.f, 0.f, 1.f}};
  for (int sweep = 0; sweep < 8; ++sweep) {
    #pragma unroll
    for (int pi = 0; pi < 3; ++pi) {
      int p = (pi == 2) ? 1 : 0;
      int q = (pi == 0) ? 1 : 2;
      float apq = A[p][q];
      if (apq == 0.0f) continue;
      float app = A[p][p], aqq = A[q][q];
      float theta = (aqq - app) / (2.0f * apq);
      float t = 1.0f / (fabsf(theta) + sqrtf(theta * theta + 1.0f));
      if (theta < 0.0f) t = -t;
      float cth = 1.0f / sqrtf(t * t + 1.0f);
      float sth = t * cth;
      A[p][p] = app - t * apq;
      A[q][q] = aqq + t * apq;
      A[p][q] = A[q][p] = 0.0f;
      int k = 3 - p - q;
      float akp = A[k][p], akq = A[k][q];
      A[k][p] = A[p][k] = cth * akp - sth * akq;
      A[k][q] = A[q][k] = sth * akp + cth * akq;
      #pragma unroll
      for (int r = 0; r < 3; ++r) {
        float vp = V[r][p], vq = V[r][q];
        V[r][p] = cth * vp - sth * vq;
        V[r][q] = sth * vp + cth * vq;
      }
    }
  }
  float l[3] = {A[0][0], A[1][1], A[2][2]};
  float a[3] = {fabsf(l[0]), fabsf(l[1]), fabsf(l[2])};
  int idx[3] = {0, 1, 2};
  if (a[idx[0]] < a[idx[1]]) { int t = idx[0]; idx[0] = idx[1]; idx[1] = t; }
  if (a[idx[1]] < a[idx[2]]) { int t = idx[1]; idx[1] = idx[2]; idx[2] = t; }
  if (a[idx[0]] < a[idx[1]]) { int t = idx[0]; idx[0] = idx[1]; idx[1] = t; }
  float S0 = fmaxf(sqrtf(a[idx[0]]), 1e-6f);
  float S1 = fmaxf(sqrtf(a[idx[1]]), 1e-6f);
  float S2 = fmaxf(sqrtf(a[idx[2]]), 1e-6f);
  float U[3][3];
  #pragma unroll
  for (int r = 0; r < 3; ++r) {
    U[r][0] = V[r][idx[0]];
    U[r][1] = V[r][idx[1]];
    U[r][2] = V[r][idx[2]];
  }
  float det = U[0][0] * (U[1][1] * U[2][2] - U[1][2] * U[2][1])
            - U[0][1] * (U[1][0] * U[2][2] - U[1][2] * U[2][0])
            + U[0][2] * (U[1][0] * U[2][1] - U[1][1] * U[2][0]);
  float f2 = (det < 0.0f) ? -1.0f : 1.0f;
  mu_o[0] = mu0; mu_o[1] = mu1; mu_o[2] = mu2; mu_o[3] = mu3;
  R_o[0] = U[0][0] * S0; R_o[1] = U[0][1] * S1; R_o[2] = U[0][2] * S2 * f2;
  R_o[3] = U[1][0] * S0; R_o[4] = U[1][1] * S1; R_o[5] = U[1][2] * S2 * f2;
  R_o[6] = U[2][0] * S0; R_o[7] = U[2][1] * S1; R_o[8] = U[2][2] * S2 * f2;
}

extern "C" void kernel_launch(void* const* d_in, const int* in_sizes, int n_in,
                              void* d_out, int out_size, void* d_ws,
                              size_t ws_size, hipStream_t stream) {
  const float4* pts = (const float4*)d_in[0];
  int n = in_sizes[0] / 4;
  float* out = (float*)d_out;
  float* outR = out + (size_t)4 * n;

  char* ws = (char*)d_ws;
  Hdr* hdr = (Hdr*)ws;
  size_t off = 256;
  unsigned* mmpart = (unsigned*)(ws + off);      off += 256 * 8 * 4;
  unsigned* bm = (unsigned*)(ws + off);          off += (size_t)WMAX * 4;
  unsigned short* rank16 = (unsigned short*)(ws + off); off += (size_t)WMAX * 2;
  unsigned* part = (unsigned*)(ws + off);        off += 4096 * 4;
  unsigned* g_cnt = (unsigned*)(ws + off);       off += 256;
  int* hit_i = (int*)(ws + off);                 off += (size_t)HITCAP * 4;
  int* hit_r = (int*)(ws + off);                 off += (size_t)HITCAP * 4;
  float* hit_w = (float*)(ws + off);             off += (size_t)HITCAP * 4;
  float* acc = (float*)(ws + off);               // n * 12 floats
  size_t needed = off + (size_t)n * 12 * 4;
  if (ws_size < needed) return;

  hipMemsetAsync(bm, 0, (size_t)WMAX * 4, stream);
  hipMemsetAsync(g_cnt, 0, 256, stream);
  hipMemsetAsync(acc, 0, (size_t)n * 12 * 4, stream);

  int nb = (n + 255) / 256;
  k_minmax<<<256, 256, 0, stream>>>(pts, n, mmpart);
  k_prep<<<1, 256, 0, stream>>>(mmpart, hdr);
  k_mark<<<nb, 256, 0, stream>>>(pts, n, hdr, bm);
  k_scanA<<<PBLK, 256, 0, stream>>>(bm, rank16, part);
  k_scanB<<<1, 256, 0, stream>>>(part, hdr);
  k_probe<<<nb, 256, 0, stream>>>(pts, n, hdr, bm, rank16, part,
                                  hit_i, hit_r, hit_w, g_cnt, acc);
  k_drain<<<512, 256, 0, stream>>>(pts, hit_i, hit_r, hit_w, g_cnt, acc);
  k_finalize<<<nb, 256, 0, stream>>>(hdr, acc, out, outR, n);
}